// Round 5
// baseline (150.844 us; speedup 1.0000x reference)
//
#include <hip/hip_runtime.h>
#include <stdint.h>

// Problem constants (fixed by setup_inputs: B=4, N_obj=8, N_v=2048)
#define NPTS 2048
#define KNN  16
#define AK   64
#define TPB  256
#define FPT  (NPTS / TPB)   // 8 points per thread
#define KPL  (NPTS / 64)    // 32 points per lane (one wave per anchor)

typedef unsigned long long u64;
typedef unsigned int u32;
typedef unsigned short u16;
#define UMAX 0xFFFFFFFFFFFFFFFFull

// Exact float32 helpers (no FMA contraction -> match reference bitwise)
__device__ __forceinline__ float sq3(float x, float y, float z) {
    return __fadd_rn(__fadd_rn(__fmul_rn(x, x), __fmul_rn(y, y)), __fmul_rn(z, z));
}

// ---------------------------------------------------------------------------
// 64-lane butterfly reductions on u64 keys, ALL-VALU.
// Stages 1,2,4,8: DPP permutations (xor1/xor2/xor4/xor8 once groups uniform).
// Stages 16,32: gfx950 v_permlane16_swap / v_permlane32_swap with self;
// reducing with BOTH results realizes the xor exchange (self-compares are
// no-ops). Harness-verified (absmax 0.0) in rounds 1-4.
// ---------------------------------------------------------------------------
template <int CTRL>
__device__ __forceinline__ u64 dpp64(u64 k) {
    const int lo = __builtin_amdgcn_update_dpp((int)(u32)k, (int)(u32)k,
                                               CTRL, 0xF, 0xF, false);
    const int hi = __builtin_amdgcn_update_dpp((int)(u32)(k >> 32),
                                               (int)(u32)(k >> 32),
                                               CTRL, 0xF, 0xF, false);
    return ((u64)(u32)hi << 32) | (u32)lo;
}

__device__ __forceinline__ void swap16_pair(u64 k, u64& a, u64& b) {
#if __has_builtin(__builtin_amdgcn_permlane16_swap)
    const u32 lo = (u32)k, hi = (u32)(k >> 32);
    const auto rl = __builtin_amdgcn_permlane16_swap(lo, lo, false, false);
    const auto rh = __builtin_amdgcn_permlane16_swap(hi, hi, false, false);
    a = ((u64)(u32)rh[0] << 32) | (u32)rl[0];
    b = ((u64)(u32)rh[1] << 32) | (u32)rl[1];
#else
    a = (u64)__shfl_xor((long long)k, 16, 64);
    b = a;
#endif
}

__device__ __forceinline__ void swap32_pair(u64 k, u64& a, u64& b) {
#if __has_builtin(__builtin_amdgcn_permlane32_swap)
    const u32 lo = (u32)k, hi = (u32)(k >> 32);
    const auto rl = __builtin_amdgcn_permlane32_swap(lo, lo, false, false);
    const auto rh = __builtin_amdgcn_permlane32_swap(hi, hi, false, false);
    a = ((u64)(u32)rh[0] << 32) | (u32)rl[0];
    b = ((u64)(u32)rh[1] << 32) | (u32)rl[1];
#else
    a = (u64)__shfl_xor((long long)k, 32, 64);
    b = a;
#endif
}

__device__ __forceinline__ u64 wave_max64(u64 k) {
    u64 o, a, b;
    o = dpp64<0xB1>(k);  if (o > k) k = o;
    o = dpp64<0x4E>(k);  if (o > k) k = o;
    o = dpp64<0x141>(k); if (o > k) k = o;
    o = dpp64<0x140>(k); if (o > k) k = o;
    swap16_pair(k, a, b); if (a > k) k = a; if (b > k) k = b;
    swap32_pair(k, a, b); if (a > k) k = a; if (b > k) k = b;
    return k;
}

__device__ __forceinline__ u64 wave_min64(u64 k) {
    u64 o, a, b;
    o = dpp64<0xB1>(k);  if (o < k) k = o;
    o = dpp64<0x4E>(k);  if (o < k) k = o;
    o = dpp64<0x141>(k); if (o < k) k = o;
    o = dpp64<0x140>(k); if (o < k) k = o;
    swap16_pair(k, a, b); if (a < k) k = a; if (b < k) k = b;
    swap32_pair(k, a, b); if (a < k) k = a; if (b < k) k = b;
    return k;
}

// ---------------------------------------------------------------------------
// FUSED kernel: 544 blocks.
//  blocks [0, n_obj):          FPS producer (byte-level R2 structure — the
//                              best-measured fps, 41.4us) publishing anchors
//                              every 8 steps (packed u16x8 = one int4 store +
//                              agent-scope release on prog[obj]).
//  blocks [n_obj, n_obj*17):   KNN consumer. Stages its LDS tile immediately
//                              (overlapped under fps), then lane0 spin-waits
//                              (s_sleep) until its 4 anchors are published.
// Co-residency: 32.3KB LDS, ~52 VGPR, 4 waves/block -> >=4 blocks/CU
// capacity vs 544/256 = 2.1 needed -> ALL blocks resident -> spin is
// deadlock-free regardless of dispatch order. prog[] is zeroed by a
// hipMemsetAsync each iteration (graph-capture-legal), so stale-workspace
// values can never release a consumer early.
// ---------------------------------------------------------------------------
__global__ __launch_bounds__(TPB) void fused_kernel(
    const float* __restrict__ pos, const float* __restrict__ vel,
    const float* __restrict__ phys, const float* __restrict__ refp,
    u16* __restrict__ anc16, int* __restrict__ prog,
    float* __restrict__ out, int n_obj) {
    const int b = blockIdx.x;
    const int t = threadIdx.x;
    const int wid = t >> 6, lane = t & 63;

    __shared__ float4 sP[NPTS];   // point tile (both roles), 32 KB
    __shared__ u64 skey[8];       // fps: double-buffered per-wave winner keys
    __shared__ float4 scrd[8];    // fps: double-buffered per-wave winner coords
    __shared__ int sAq[4];        // knn: this block's 4 anchor indices

    if (b < n_obj) {
        // ================= FPS role (R2 structure, verified) =================
        const int obj = b;
        const float* pts = pos + (size_t)obj * NPTS * 3;
        float px[FPT], py[FPT], pz[FPT], mind[FPT];
        #pragma unroll
        for (int i = 0; i < FPT; i++) {
            const int j = t + i * TPB;
            const float x = pts[j * 3 + 0];
            const float y = pts[j * 3 + 1];
            const float z = pts[j * 3 + 2];
            px[i] = x; py[i] = y; pz[i] = z;
            sP[j] = make_float4(x, y, z, 0.f);
        }
        __syncthreads();

        // anchor accumulator: 8 most recent anchor ids in two u64s (16b each)
        u64 ap0 = 0, ap1 = 0;
        #define PUSH_AID(v) { ap0 = (ap0 >> 16) | (ap1 << 48); \
                              ap1 = (ap1 >> 16) | ((u64)(u16)(v) << 48); }
        PUSH_AID(0);   // anchor 0 is point 0

        u64 key;
        {
            const float4 c0 = sP[0];   // broadcast read
            float bv = -1.0f; u32 bj = 0;
            #pragma unroll
            for (int i = 0; i < FPT; i++) {
                const float d2 = sq3(__fsub_rn(px[i], c0.x), __fsub_rn(py[i], c0.y),
                                     __fsub_rn(pz[i], c0.z));
                mind[i] = d2;
                if (d2 > bv) { bv = d2; bj = (u32)(t + i * TPB); }  // smallest j on ties
            }
            // mind >= 0 -> float bits order-monotonic; ~j -> smaller j wins ties
            key = ((u64)__float_as_uint(bv) << 32) | (u32)(~bj);
        }

        #pragma unroll 1
        for (int s = 1; s < AK; s++) {
            const u64 wk = wave_max64(key);     // all lanes hold wave-winner
            const int side = (s & 1) * 4;
            if (lane == 0) {
                const int widx = (int)(~(u32)wk);
                skey[side + wid] = wk;
                scrd[side + wid] = sP[widx];    // 1x broadcast ds_read_b128
            }
            __syncthreads();   // only barrier per step
            u64 ka = skey[side + 0];
            float4 ca = scrd[side + 0];
            { const u64 k1 = skey[side + 1]; const float4 q = scrd[side + 1];
              if (k1 > ka) { ka = k1; ca = q; } }
            { const u64 k2 = skey[side + 2]; const float4 q = scrd[side + 2];
              if (k2 > ka) { ka = k2; ca = q; } }
            { const u64 k3 = skey[side + 3]; const float4 q = scrd[side + 3];
              if (k3 > ka) { ka = k3; ca = q; } }

            const int aid = (int)(~(u32)ka);
            PUSH_AID(aid);
            if ((s & 7) == 7 && t == 0) {   // publish anchors s-7..s
                const int4 v = make_int4((int)(u32)ap0, (int)(u32)(ap0 >> 32),
                                         (int)(u32)ap1, (int)(u32)(ap1 >> 32));
                *(int4*)(anc16 + obj * AK + (s - 7)) = v;
                __threadfence();   // order the int4 store before the flag
                __hip_atomic_store(&prog[obj], s + 1, __ATOMIC_RELEASE,
                                   __HIP_MEMORY_SCOPE_AGENT);
            }
            if (s == AK - 1) break;   // (63&7)==7 -> final batch published above

            // fused min-update + argmax scan (exact (p-b)^2 like lax.scan)
            float bv = -1.0f; u32 bj = 0;
            #pragma unroll
            for (int i = 0; i < FPT; i++) {
                const float d2 = sq3(__fsub_rn(px[i], ca.x), __fsub_rn(py[i], ca.y),
                                     __fsub_rn(pz[i], ca.z));
                const float nm = fminf(mind[i], d2);
                mind[i] = nm;
                if (nm > bv) { bv = nm; bj = (u32)(t + i * TPB); }
            }
            key = ((u64)__float_as_uint(bv) << 32) | (u32)(~bj);
        }
        return;
    }

    // ================= KNN role (verified body, fused delivery) =============
    const int g4 = b - n_obj;           // 0..511
    const int obj = g4 >> 4;
    const int q = g4 & 15;
    const int g = obj * AK + q * 4 + wid;   // global anchor id (== old mapping)

    const float* pts = pos + (size_t)obj * NPTS * 3;
    #pragma unroll
    for (int i = 0; i < FPT; i++) {
        const int j = t + i * TPB;
        const float x = pts[j * 3 + 0];
        const float y = pts[j * 3 + 1];
        const float z = pts[j * 3 + 2];
        sP[j] = make_float4(x, y, z, sq3(x, y, z));
    }
    if (t == 0) {
        const int need = q * 4 + 4;      // anchors q*4..q*4+3 published
        while (__hip_atomic_load(&prog[obj], __ATOMIC_ACQUIRE,
                                 __HIP_MEMORY_SCOPE_AGENT) < need)
            __builtin_amdgcn_s_sleep(4);
        const u16* ap = anc16 + obj * AK + q * 4;
        sAq[0] = ap[0]; sAq[1] = ap[1]; sAq[2] = ap[2]; sAq[3] = ap[3];
    }
    __syncthreads();            // staging + anchor delivery barrier
    const int a = sAq[wid];

    const float4 ca = sP[a];
    const float ax = ca.x, ay = ca.y, az = ca.z;
    const float sqa = ca.w;     // identical bits to reference's sq[a]

    // d2 row exactly as reference: (sq_a + sq_j) - 2*dot, sign-flip sortable.
    u64 k[KPL];
    #pragma unroll
    for (int i = 0; i < KPL; i++) {
        const int j = lane + i * 64;
        const float4 p = sP[j];
        const float dot = __fadd_rn(
            __fadd_rn(__fmul_rn(ax, p.x), __fmul_rn(ay, p.y)), __fmul_rn(az, p.z));
        const float d2 = __fsub_rn(__fadd_rn(sqa, p.w), __fmul_rn(2.0f, dot));
        u32 bb = __float_as_uint(d2);
        bb ^= (bb & 0x80000000u) ? 0xFFFFFFFFu : 0x80000000u;
        k[i] = (j == a) ? UMAX : (((u64)bb << 32) | (u32)j);
    }

    // per-lane 4 smallest, ascending: c0 < c1 < c2 < c3 (keys unique)
    u64 c0 = UMAX, c1 = UMAX, c2 = UMAX, c3 = UMAX;
    #pragma unroll
    for (int i = 0; i < KPL; i++) c0 = (k[i] < c0) ? k[i] : c0;
    #pragma unroll
    for (int i = 0; i < KPL; i++) {
        const u64 v = (k[i] > c0) ? k[i] : UMAX; c1 = (v < c1) ? v : c1;
    }
    #pragma unroll
    for (int i = 0; i < KPL; i++) {
        const u64 v = (k[i] > c1) ? k[i] : UMAX; c2 = (v < c2) ? v : c2;
    }
    #pragma unroll
    for (int i = 0; i < KPL; i++) {
        const u64 v = (k[i] > c2) ? k[i] : UMAX; c3 = (v < c3) ? v : c3;
    }

    float accx = 0.f, accy = 0.f, accz = 0.f;
    u64 thr = 0;
    float4 cw;
    {
        // round 0: every lane has >=4 real candidates -> no refill possible
        const u64 w = wave_min64(c0);
        cw = sP[(int)(u32)w];              // issue read; consumed next round
        if (c0 == w) { thr = c0; c0 = c1; c1 = c2; c2 = c3; c3 = UMAX; }
    }
    #pragma unroll 1
    for (int r = 1; r < KNN; r++) {
        if (c0 == UMAX) {   // rare refill: 4 smallest keys > thr
            #pragma unroll
            for (int i = 0; i < KPL; i++) {
                const u64 v = (k[i] > thr) ? k[i] : UMAX; c0 = (v < c0) ? v : c0;
            }
            #pragma unroll
            for (int i = 0; i < KPL; i++) {
                const u64 v = (k[i] > c0) ? k[i] : UMAX; c1 = (v < c1) ? v : c1;
            }
            #pragma unroll
            for (int i = 0; i < KPL; i++) {
                const u64 v = (k[i] > c1) ? k[i] : UMAX; c2 = (v < c2) ? v : c2;
            }
            #pragma unroll
            for (int i = 0; i < KPL; i++) {
                const u64 v = (k[i] > c2) ? k[i] : UMAX; c3 = (v < c3) ? v : c3;
            }
        }
        const u64 w = wave_min64(c0);       // global min; ties impossible
        const float4 cn = sP[(int)(u32)w];  // issue this round's read...
        // ...and accumulate LAST round's winner under its latency (exact order)
        accx = __fadd_rn(accx, __fsub_rn(cw.x, ax));
        accy = __fadd_rn(accy, __fsub_rn(cw.y, ay));
        accz = __fadd_rn(accz, __fsub_rn(cw.z, az));
        cw = cn;
        if (c0 == w) {                      // exactly one lane pops
            thr = c0; c0 = c1; c1 = c2; c2 = c3; c3 = UMAX;
        }
    }
    accx = __fadd_rn(accx, __fsub_rn(cw.x, ax));
    accy = __fadd_rn(accy, __fsub_rn(cw.y, ay));
    accz = __fadd_rn(accz, __fsub_rn(cw.z, az));

    if (lane == 0) {
        float* o = out + (size_t)g * 12;
        o[0] = __fmul_rn(accx, 0.0625f);   // /16 exact as *2^-4
        o[1] = __fmul_rn(accy, 0.0625f);
        o[2] = __fmul_rn(accz, 0.0625f);
        const size_t base = (size_t)obj * NPTS * 3 + (size_t)a * 3;
        o[3] = vel[base + 0];
        o[4] = vel[base + 1];
        o[5] = vel[base + 2];
        o[6] = __fsub_rn(pos[base + 0], refp[base + 0]);
        o[7] = __fsub_rn(pos[base + 1], refp[base + 1]);
        o[8] = __fsub_rn(pos[base + 2], refp[base + 2]);
        const float* ph = phys + (size_t)obj * 3;
        o[9]  = ph[0];
        o[10] = ph[1];
        o[11] = ph[2];
    }
}

extern "C" void kernel_launch(void* const* d_in, const int* in_sizes, int n_in,
                              void* d_out, int out_size, void* d_ws, size_t ws_size,
                              hipStream_t stream) {
    const float* pos  = (const float*)d_in[0];  // (4,8,2048,3)
    const float* vel  = (const float*)d_in[1];  // (4,8,2048,3)
    const float* phys = (const float*)d_in[2];  // (4,8,3)
    const float* refp = (const float*)d_in[3];  // (4,8,2048,3)
    float* out = (float*)d_out;                 // (4,8,64,12)

    const int n_obj = in_sizes[2] / 3;          // 32 objects
    u16* anc16 = (u16*)d_ws;                    // 32*64 u16 = 4 KB
    int* prog = (int*)((char*)d_ws + n_obj * AK * sizeof(u16));  // 32 ints

    // zero the progress flags each iteration (graph-capture-legal async op);
    // guarantees no stale-workspace release of consumers.
    hipMemsetAsync(prog, 0, n_obj * sizeof(int), stream);

    fused_kernel<<<n_obj * 17, TPB, 0, stream>>>(pos, vel, phys, refp,
                                                 anc16, prog, out, n_obj);
}

// Round 6
// 106.591 us; speedup vs baseline: 1.4152x; 1.4152x over previous
//
#include <hip/hip_runtime.h>
#include <stdint.h>

// Problem constants (fixed by setup_inputs: B=4, N_obj=8, N_v=2048)
#define NPTS 2048
#define KNN  16
#define AK   64
#define TPB  256
#define FPT  (NPTS / TPB)   // 8 points per thread
#define KPL  (NPTS / 64)    // 32 points per lane (one wave per anchor)

typedef unsigned long long u64;
typedef unsigned int u32;
typedef unsigned short u16;
#define UMAX 0xFFFFFFFFFFFFFFFFull

// Exact float32 helpers (no FMA contraction -> match reference bitwise)
__device__ __forceinline__ float sq3(float x, float y, float z) {
    return __fadd_rn(__fadd_rn(__fmul_rn(x, x), __fmul_rn(y, y)), __fmul_rn(z, z));
}

// ---------------------------------------------------------------------------
// 64-lane butterfly reductions on u64 keys, ALL-VALU.
// Stages 1,2,4,8: DPP permutations (xor1/xor2/xor4/xor8 once groups uniform).
// Stages 16,32: gfx950 v_permlane16_swap / v_permlane32_swap with self;
// reducing with BOTH results realizes the xor exchange (self-compares are
// no-ops). Harness-verified (absmax 0.0) in rounds 1-5.
// ---------------------------------------------------------------------------
template <int CTRL>
__device__ __forceinline__ u64 dpp64(u64 k) {
    const int lo = __builtin_amdgcn_update_dpp((int)(u32)k, (int)(u32)k,
                                               CTRL, 0xF, 0xF, false);
    const int hi = __builtin_amdgcn_update_dpp((int)(u32)(k >> 32),
                                               (int)(u32)(k >> 32),
                                               CTRL, 0xF, 0xF, false);
    return ((u64)(u32)hi << 32) | (u32)lo;
}

__device__ __forceinline__ void swap16_pair(u64 k, u64& a, u64& b) {
#if __has_builtin(__builtin_amdgcn_permlane16_swap)
    const u32 lo = (u32)k, hi = (u32)(k >> 32);
    const auto rl = __builtin_amdgcn_permlane16_swap(lo, lo, false, false);
    const auto rh = __builtin_amdgcn_permlane16_swap(hi, hi, false, false);
    a = ((u64)(u32)rh[0] << 32) | (u32)rl[0];
    b = ((u64)(u32)rh[1] << 32) | (u32)rl[1];
#else
    a = (u64)__shfl_xor((long long)k, 16, 64);
    b = a;
#endif
}

__device__ __forceinline__ void swap32_pair(u64 k, u64& a, u64& b) {
#if __has_builtin(__builtin_amdgcn_permlane32_swap)
    const u32 lo = (u32)k, hi = (u32)(k >> 32);
    const auto rl = __builtin_amdgcn_permlane32_swap(lo, lo, false, false);
    const auto rh = __builtin_amdgcn_permlane32_swap(hi, hi, false, false);
    a = ((u64)(u32)rh[0] << 32) | (u32)rl[0];
    b = ((u64)(u32)rh[1] << 32) | (u32)rl[1];
#else
    a = (u64)__shfl_xor((long long)k, 32, 64);
    b = a;
#endif
}

__device__ __forceinline__ u64 wave_max64(u64 k) {
    u64 o, a, b;
    o = dpp64<0xB1>(k);  if (o > k) k = o;
    o = dpp64<0x4E>(k);  if (o > k) k = o;
    o = dpp64<0x141>(k); if (o > k) k = o;
    o = dpp64<0x140>(k); if (o > k) k = o;
    swap16_pair(k, a, b); if (a > k) k = a; if (b > k) k = b;
    swap32_pair(k, a, b); if (a > k) k = a; if (b > k) k = b;
    return k;
}

__device__ __forceinline__ u64 wave_min64(u64 k) {
    u64 o, a, b;
    o = dpp64<0xB1>(k);  if (o < k) k = o;
    o = dpp64<0x4E>(k);  if (o < k) k = o;
    o = dpp64<0x141>(k); if (o < k) k = o;
    o = dpp64<0x140>(k); if (o < k) k = o;
    swap16_pair(k, a, b); if (a < k) k = a; if (b < k) k = b;
    swap32_pair(k, a, b); if (a < k) k = a; if (b < k) k = b;
    return k;
}

// ---------------------------------------------------------------------------
// FUSED kernel, data-as-flag edition. 544 blocks.
//  blocks [0, n_obj):        FPS producer — R2's best-measured structure.
//    Every 4 steps, publishes the completed anchor quad as ONE relaxed
//    64-bit agent-scope atomic store (4 x u16 packed). No fence, no
//    threadfence, no release: the payload IS the readiness signal.
//    Nonzero-proof: FPS anchors are distinct, so at most one of any 4
//    consecutive anchors can be index 0 -> the packed word is never 0.
//  blocks [n_obj, n_obj*17): KNN consumer for one anchor quad. Stages its
//    LDS tile immediately (overlapped under fps), then lane0 polls ITS OWN
//    u64 (512 distinct words spread over 32 cachelines -> no hot line) with
//    relaxed agent-scope loads + s_sleep until nonzero.
// Co-residency: 32.9KB LDS, ~52 VGPR -> 4 blocks/CU capacity; 544 blocks
// over 256 CUs -> ALL blocks resident regardless of dispatch order -> the
// spin is deadlock-free. aq[] is zeroed by hipMemsetAsync each iteration
// (graph-capture-legal), so stale workspace can never release a consumer.
// vs R5 (98.7us): removed per-publish __threadfence (buffer_wbl2 on the fps
// critical path) and the single-cacheline ACQUIRE polling storm — the two
// diagnosed regressions.
// ---------------------------------------------------------------------------
__global__ __launch_bounds__(TPB) void fused_kernel(
    const float* __restrict__ pos, const float* __restrict__ vel,
    const float* __restrict__ phys, const float* __restrict__ refp,
    u64* __restrict__ aq, float* __restrict__ out, int n_obj) {
    const int b = blockIdx.x;
    const int t = threadIdx.x;
    const int wid = t >> 6, lane = t & 63;

    __shared__ float4 sP[NPTS];   // point tile (both roles), 32 KB
    __shared__ u64 skey[8];       // fps: double-buffered per-wave winner keys
    __shared__ float4 scrd[8];    // fps: double-buffered per-wave winner coords
    __shared__ u64 sQ;            // knn: the polled quad word

    if (b < n_obj) {
        // ================= FPS role (R2 structure, verified) =================
        const int obj = b;
        const float* pts = pos + (size_t)obj * NPTS * 3;
        float px[FPT], py[FPT], pz[FPT], mind[FPT];
        #pragma unroll
        for (int i = 0; i < FPT; i++) {
            const int j = t + i * TPB;
            const float x = pts[j * 3 + 0];
            const float y = pts[j * 3 + 1];
            const float z = pts[j * 3 + 2];
            px[i] = x; py[i] = y; pz[i] = z;
            sP[j] = make_float4(x, y, z, 0.f);
        }
        __syncthreads();

        // quad accumulator: 4 most recent anchor ids, earliest in low 16 bits
        u64 qacc = 0;
        #define PUSH_AID(v) qacc = (qacc >> 16) | ((u64)(u16)(v) << 48)
        PUSH_AID(0);   // anchor 0 is point 0

        u64 key;
        {
            const float4 c0 = sP[0];   // broadcast read
            float bv = -1.0f; u32 bj = 0;
            #pragma unroll
            for (int i = 0; i < FPT; i++) {
                const float d2 = sq3(__fsub_rn(px[i], c0.x), __fsub_rn(py[i], c0.y),
                                     __fsub_rn(pz[i], c0.z));
                mind[i] = d2;
                if (d2 > bv) { bv = d2; bj = (u32)(t + i * TPB); }  // smallest j on ties
            }
            // mind >= 0 -> float bits order-monotonic; ~j -> smaller j wins ties
            key = ((u64)__float_as_uint(bv) << 32) | (u32)(~bj);
        }

        #pragma unroll 1
        for (int s = 1; s < AK; s++) {
            const u64 wk = wave_max64(key);     // all lanes hold wave-winner
            const int side = (s & 1) * 4;
            if (lane == 0) {
                const int widx = (int)(~(u32)wk);
                skey[side + wid] = wk;
                scrd[side + wid] = sP[widx];    // 1x broadcast ds_read_b128
            }
            __syncthreads();   // only barrier per step
            u64 ka = skey[side + 0];
            float4 ca = scrd[side + 0];
            { const u64 k1 = skey[side + 1]; const float4 q = scrd[side + 1];
              if (k1 > ka) { ka = k1; ca = q; } }
            { const u64 k2 = skey[side + 2]; const float4 q = scrd[side + 2];
              if (k2 > ka) { ka = k2; ca = q; } }
            { const u64 k3 = skey[side + 3]; const float4 q = scrd[side + 3];
              if (k3 > ka) { ka = k3; ca = q; } }

            PUSH_AID((int)(~(u32)ka));
            if ((s & 3) == 3 && t == 0) {   // publish quad s>>2 (anchors s-3..s)
                __hip_atomic_store(&aq[obj * 16 + (s >> 2)], qacc,
                                   __ATOMIC_RELAXED, __HIP_MEMORY_SCOPE_AGENT);
            }
            if (s == AK - 1) break;   // (63&3)==3 -> quad 15 published above

            // fused min-update + argmax scan (exact (p-b)^2 like lax.scan)
            float bv = -1.0f; u32 bj = 0;
            #pragma unroll
            for (int i = 0; i < FPT; i++) {
                const float d2 = sq3(__fsub_rn(px[i], ca.x), __fsub_rn(py[i], ca.y),
                                     __fsub_rn(pz[i], ca.z));
                const float nm = fminf(mind[i], d2);
                mind[i] = nm;
                if (nm > bv) { bv = nm; bj = (u32)(t + i * TPB); }
            }
            key = ((u64)__float_as_uint(bv) << 32) | (u32)(~bj);
        }
        return;
    }

    // ================= KNN role (verified body, data-as-flag delivery) ======
    const int g4 = b - n_obj;           // 0..511
    const int obj = g4 >> 4;
    const int q = g4 & 15;
    const int g = obj * AK + q * 4 + wid;   // global anchor id (== old mapping)

    const float* pts = pos + (size_t)obj * NPTS * 3;
    #pragma unroll
    for (int i = 0; i < FPT; i++) {
        const int j = t + i * TPB;
        const float x = pts[j * 3 + 0];
        const float y = pts[j * 3 + 1];
        const float z = pts[j * 3 + 2];
        sP[j] = make_float4(x, y, z, sq3(x, y, z));
    }
    if (t == 0) {
        u64 v;
        for (;;) {
            v = __hip_atomic_load(&aq[obj * 16 + q], __ATOMIC_RELAXED,
                                  __HIP_MEMORY_SCOPE_AGENT);
            if (v != 0) break;
            __builtin_amdgcn_s_sleep(2);
        }
        sQ = v;
    }
    __syncthreads();            // staging + anchor delivery barrier
    const int a = (int)((sQ >> (16 * wid)) & 0xFFFF);

    const float4 ca = sP[a];
    const float ax = ca.x, ay = ca.y, az = ca.z;
    const float sqa = ca.w;     // identical bits to reference's sq[a]

    // d2 row exactly as reference: (sq_a + sq_j) - 2*dot, sign-flip sortable.
    u64 k[KPL];
    #pragma unroll
    for (int i = 0; i < KPL; i++) {
        const int j = lane + i * 64;
        const float4 p = sP[j];
        const float dot = __fadd_rn(
            __fadd_rn(__fmul_rn(ax, p.x), __fmul_rn(ay, p.y)), __fmul_rn(az, p.z));
        const float d2 = __fsub_rn(__fadd_rn(sqa, p.w), __fmul_rn(2.0f, dot));
        u32 bb = __float_as_uint(d2);
        bb ^= (bb & 0x80000000u) ? 0xFFFFFFFFu : 0x80000000u;
        k[i] = (j == a) ? UMAX : (((u64)bb << 32) | (u32)j);
    }

    // per-lane 4 smallest, ascending: c0 < c1 < c2 < c3 (keys unique)
    u64 c0 = UMAX, c1 = UMAX, c2 = UMAX, c3 = UMAX;
    #pragma unroll
    for (int i = 0; i < KPL; i++) c0 = (k[i] < c0) ? k[i] : c0;
    #pragma unroll
    for (int i = 0; i < KPL; i++) {
        const u64 v = (k[i] > c0) ? k[i] : UMAX; c1 = (v < c1) ? v : c1;
    }
    #pragma unroll
    for (int i = 0; i < KPL; i++) {
        const u64 v = (k[i] > c1) ? k[i] : UMAX; c2 = (v < c2) ? v : c2;
    }
    #pragma unroll
    for (int i = 0; i < KPL; i++) {
        const u64 v = (k[i] > c2) ? k[i] : UMAX; c3 = (v < c3) ? v : c3;
    }

    float accx = 0.f, accy = 0.f, accz = 0.f;
    u64 thr = 0;
    float4 cw;
    {
        // round 0: every lane has >=4 real candidates -> no refill possible
        const u64 w = wave_min64(c0);
        cw = sP[(int)(u32)w];              // issue read; consumed next round
        if (c0 == w) { thr = c0; c0 = c1; c1 = c2; c2 = c3; c3 = UMAX; }
    }
    #pragma unroll 1
    for (int r = 1; r < KNN; r++) {
        if (c0 == UMAX) {   // rare refill: 4 smallest keys > thr
            #pragma unroll
            for (int i = 0; i < KPL; i++) {
                const u64 v = (k[i] > thr) ? k[i] : UMAX; c0 = (v < c0) ? v : c0;
            }
            #pragma unroll
            for (int i = 0; i < KPL; i++) {
                const u64 v = (k[i] > c0) ? k[i] : UMAX; c1 = (v < c1) ? v : c1;
            }
            #pragma unroll
            for (int i = 0; i < KPL; i++) {
                const u64 v = (k[i] > c1) ? k[i] : UMAX; c2 = (v < c2) ? v : c2;
            }
            #pragma unroll
            for (int i = 0; i < KPL; i++) {
                const u64 v = (k[i] > c2) ? k[i] : UMAX; c3 = (v < c3) ? v : c3;
            }
        }
        const u64 w = wave_min64(c0);       // global min; ties impossible
        const float4 cn = sP[(int)(u32)w];  // issue this round's read...
        // ...and accumulate LAST round's winner under its latency (exact order)
        accx = __fadd_rn(accx, __fsub_rn(cw.x, ax));
        accy = __fadd_rn(accy, __fsub_rn(cw.y, ay));
        accz = __fadd_rn(accz, __fsub_rn(cw.z, az));
        cw = cn;
        if (c0 == w) {                      // exactly one lane pops
            thr = c0; c0 = c1; c1 = c2; c2 = c3; c3 = UMAX;
        }
    }
    accx = __fadd_rn(accx, __fsub_rn(cw.x, ax));
    accy = __fadd_rn(accy, __fsub_rn(cw.y, ay));
    accz = __fadd_rn(accz, __fsub_rn(cw.z, az));

    if (lane == 0) {
        float* o = out + (size_t)g * 12;
        o[0] = __fmul_rn(accx, 0.0625f);   // /16 exact as *2^-4
        o[1] = __fmul_rn(accy, 0.0625f);
        o[2] = __fmul_rn(accz, 0.0625f);
        const size_t base = (size_t)obj * NPTS * 3 + (size_t)a * 3;
        o[3] = vel[base + 0];
        o[4] = vel[base + 1];
        o[5] = vel[base + 2];
        o[6] = __fsub_rn(pos[base + 0], refp[base + 0]);
        o[7] = __fsub_rn(pos[base + 1], refp[base + 1]);
        o[8] = __fsub_rn(pos[base + 2], refp[base + 2]);
        const float* ph = phys + (size_t)obj * 3;
        o[9]  = ph[0];
        o[10] = ph[1];
        o[11] = ph[2];
    }
}

extern "C" void kernel_launch(void* const* d_in, const int* in_sizes, int n_in,
                              void* d_out, int out_size, void* d_ws, size_t ws_size,
                              hipStream_t stream) {
    const float* pos  = (const float*)d_in[0];  // (4,8,2048,3)
    const float* vel  = (const float*)d_in[1];  // (4,8,2048,3)
    const float* phys = (const float*)d_in[2];  // (4,8,3)
    const float* refp = (const float*)d_in[3];  // (4,8,2048,3)
    float* out = (float*)d_out;                 // (4,8,64,12)

    const int n_obj = in_sizes[2] / 3;          // 32 objects
    u64* aq = (u64*)d_ws;                       // 32*16 u64 = 4 KB quad slots

    // zero the quad slots each iteration (graph-capture-legal async op);
    // guarantees no stale-workspace release of consumers.
    hipMemsetAsync(aq, 0, (size_t)n_obj * 16 * sizeof(u64), stream);

    fused_kernel<<<n_obj * 17, TPB, 0, stream>>>(pos, vel, phys, refp,
                                                 aq, out, n_obj);
}